// Round 10
// baseline (228.817 us; speedup 1.0000x reference)
//
#include <hip/hip_runtime.h>

// B=4, L=256, E=128, H=8, D=16, NU=512, NT=256. All I/O fp32.
// 3 dispatches:
//   1. pre_fused : 9 projections (K transposed) + CI transpose + weight-fold + gstat zero
//   2. attn_epi  : ONE query row per block (1024 blocks): ta + du + uu attention (all
//                  heads) -> cat in LDS -> epilogue y = C @ cat + bias -> BN stat atomics
//   3. bn_apply  : (y - mean)*rsqrt(var+eps)*g + b, ReLU

struct PreArgs {
    const float* x[9]; const float* W[9]; const float* bia[9]; float* out[9];
    int Kdim[9]; int transNb[9];     // 0 = row-major out; else n-per-b for [b][e][n] layout
    const float* CIMat; float* cit;
    const float* dim_w; const float* dim_b;
    const float* uu_ow; const float* uu_ob;
    const float* ta_ow; const float* ta_ob;
    const float* du_ow; const float* du_ob;
    float* Cuu; float* Cta; float* Cdu; float* bcomb;
    float* gstat;                    // 256 floats (zeroed here)
};

// tasks: [0,1408) proj (8 rows each), [1408,2432) CI transpose, [2432,2560) fold
__global__ __launch_bounds__(256) void pre_fused(PreArgs A)
{
    __shared__ __align__(16) float smem[1056];
    int bid = blockIdx.x, tid = threadIdx.x;
    if (bid == 0) A.gstat[tid] = 0.f;

    if (bid < 1408) {
        int task, mblk;
        if (bid < 896) { task = bid >> 7; mblk = bid & 127; }
        else { int r = bid - 896; task = 7 + (r >> 8); mblk = r & 255; }
        int Kd = A.Kdim[task];
        const float* x = A.x[task];
        int m0 = mblk * 8;
        if (Kd == 128) {
            ((float4*)smem)[tid] = ((const float4*)(x + (size_t)m0 * 128))[tid];
        } else {
            for (int i = tid; i < 1024; i += 256) {
                int r = i >> 7, c = i & 127;
                smem[i] = (c < Kd) ? x[(size_t)(m0 + r) * Kd + c] : 0.f;
            }
        }
        __syncthreads();
        int e = tid & 127, half = tid >> 7;
        const float4* w4 = (const float4*)(A.W[task] + (size_t)e * 128);
        const float4* xs4 = (const float4*)smem + half * 4 * 32;
        float acc[4];
        float bv = A.bia[task][e];
#pragma unroll
        for (int r = 0; r < 4; ++r) acc[r] = bv;
#pragma unroll 8
        for (int c = 0; c < 32; ++c) {
            float4 w = w4[c];
#pragma unroll
            for (int r = 0; r < 4; ++r) {
                float4 xv = xs4[r * 32 + c];
                acc[r] += w.x * xv.x + w.y * xv.y + w.z * xv.z + w.w * xv.w;
            }
        }
        int nb = A.transNb[task];
        float* op = A.out[task];
        if (nb == 0) {
#pragma unroll
            for (int r = 0; r < 4; ++r)
                op[(size_t)(m0 + half * 4 + r) * 128 + e] = acc[r];
        } else {
            int b = m0 / nb, nloc = m0 - b * nb;
            float* o = op + ((size_t)b * 128 + e) * nb + nloc + half * 4;
            float4 v = { acc[0], acc[1], acc[2], acc[3] };
            *(float4*)o = v;
        }
    } else if (bid < 2432) {
        int tb = bid - 1408;
        int b = tb >> 8, tt = tb & 255;
        int n0 = (tt >> 4) * 32, c0 = (tt & 15) * 32;
        float (*tile)[33] = (float(*)[33])smem;
        int tx = tid & 31, ty = tid >> 5;   // 32 x 8
        const float* src = A.CIMat + (size_t)b * 262144;
        float* dst = A.cit + (size_t)b * 262144;
#pragma unroll
        for (int i = ty; i < 32; i += 8)
            tile[i][tx] = src[(size_t)(n0 + i) * 512 + c0 + tx];
        __syncthreads();
#pragma unroll
        for (int i = ty; i < 32; i += 8)
            dst[(size_t)(c0 + i) * 512 + n0 + tx] = tile[tx][i];
    } else {
        float* ds = smem;
        float* red = smem + 384;
        int e = bid - 2432, k = tid;
        if (k < 128) {
            ds[k]       = A.dim_w[(size_t)e * 384 + k];
            ds[128 + k] = A.dim_w[(size_t)e * 384 + 128 + k];
            ds[256 + k] = A.dim_w[(size_t)e * 384 + 256 + k];
        }
        __syncthreads();
        if (k < 128) {
            float cu = 0.f, ct = 0.f, cd = 0.f;
#pragma unroll 4
            for (int j = 0; j < 128; ++j) {
                cu += ds[j]       * A.uu_ow[(size_t)j * 128 + k];
                ct += ds[128 + j] * A.ta_ow[(size_t)j * 128 + k];
                cd += ds[256 + j] * A.du_ow[(size_t)j * 128 + k];
            }
            A.Cuu[(size_t)e * 128 + k] = cu;
            A.Cta[(size_t)e * 128 + k] = ct;
            A.Cdu[(size_t)e * 128 + k] = cd;
            red[k] = ds[k] * A.uu_ob[k] + ds[128 + k] * A.ta_ob[k] + ds[256 + k] * A.du_ob[k];
        }
        __syncthreads();
        for (int off = 64; off; off >>= 1) {
            if (k < off) red[k] += red[k + off];
            __syncthreads();
        }
        if (k == 0) A.bcomb[e] = A.dim_b[e] + red[0];
    }
}

struct AttnArgs {
    const float* qd; const float* kbaseT; const float* vbase; const float* cit;
    const float* qta; const float* ktaT; const float* vta;
    const float* qdu; const float* kduT; const float* vdu;
    const float* uu_in_w;
    const float* Cuu; const float* Cta; const float* Cdu; const float* bcomb;
    float* y; float* gstat;
};

// ONE query row per block. LDS (floats):
//   qs 128 | sc 4096 | ci0 512 | ci1 512 | cat 384 | vpart 512 | misc 40  ~= 24.8 KB
__global__ __launch_bounds__(256) void attn_epi(AttnArgs A)
{
    __shared__ __align__(16) float smem[6184];
    int bid = blockIdx.x, tid = threadIdx.x;
    int b = bid >> 8, bl = bid;
    float* qs    = smem;            // 128
    float* sc    = smem + 128;      // 4096 (uu: [h][512]; ta/du: [h][256])
    float* ci0s  = smem + 4224;     // 512
    float* ci1s  = smem + 4736;     // 512
    float* cat   = smem + 5248;     // 384
    float* vpart = smem + 5632;     // 512
    float* den   = smem + 6144;     // 8
    float* hs0   = den + 8;
    float* hs1   = hs0 + 8;
    float* qkA   = hs1 + 8;
    float* qkB   = qkA + 8;

    // ================= ta and du stages (N=256) =================
    for (int kind = 0; kind < 2; ++kind) {
        const float* q  = kind ? A.qdu  : A.qta;
        const float* kT = kind ? A.kduT : A.ktaT;
        const float* v  = kind ? A.vdu  : A.vta;
        int catoff = 128 + kind * 128;
        __syncthreads();
        if (tid < 128) qs[tid] = q[(size_t)bl * 128 + tid];
        __syncthreads();
        {   // scores: thread = (head-pair hg, 4 consecutive n)
            int hg = tid >> 6, n4 = (tid & 63) * 4;
            const float* kp = kT + (size_t)b * 128 * 256 + n4;
            float4 acc[2] = { {0,0,0,0}, {0,0,0,0} };
#pragma unroll
            for (int hh = 0; hh < 2; ++hh) {
                int h = hg * 2 + hh;
#pragma unroll
                for (int d = 0; d < 16; ++d) {
                    int e = h * 16 + d;
                    float4 kv = *(const float4*)(kp + (size_t)e * 256);
                    float qv = qs[e];
                    acc[hh].x += qv * kv.x; acc[hh].y += qv * kv.y;
                    acc[hh].z += qv * kv.z; acc[hh].w += qv * kv.w;
                }
            }
#pragma unroll
            for (int hh = 0; hh < 2; ++hh) {
                int h = hg * 2 + hh;
                float4 s = { acc[hh].x * 0.25f, acc[hh].y * 0.25f,
                             acc[hh].z * 0.25f, acc[hh].w * 0.25f };
                *(float4*)(sc + h * 256 + n4) = s;
            }
        }
        __syncthreads();
        {   // softmax: 8 head-groups x 32 lanes
            int g = tid >> 5, j = tid & 31;
            float* row = sc + g * 256;
            float mx = -1e30f;
#pragma unroll
            for (int n = j; n < 256; n += 32) mx = fmaxf(mx, row[n]);
#pragma unroll
            for (int off = 16; off; off >>= 1) mx = fmaxf(mx, __shfl_down(mx, off, 32));
            mx = __shfl(mx, 0, 32);
            float s = 0.f;
#pragma unroll
            for (int n = j; n < 256; n += 32) {
                float ev = __expf(row[n] - mx);
                row[n] = ev; s += ev;
            }
#pragma unroll
            for (int off = 16; off; off >>= 1) s += __shfl_down(s, off, 32);
            if (j == 0) den[g] = s;
        }
        __syncthreads();
        {   // V pass partials: (col, n-half)
            int col = tid & 127, nh = tid >> 7;
            const float* vcol = v + ((size_t)b * 256 + nh * 128) * 128 + col;
            const float* p = sc + (col >> 4) * 256 + nh * 128;
            float a = 0.f;
#pragma unroll 8
            for (int n = 0; n < 128; ++n) a += p[n] * vcol[(size_t)n * 128];
            vpart[nh * 128 + col] = a;
        }
        __syncthreads();
        if (tid < 128)
            cat[catoff + tid] = (vpart[tid] + vpart[128 + tid]) / den[tid >> 4];
    }

    // ================= uu stage (N=512, rank-2 ci correction) =================
    __syncthreads();
    if (tid < 128) qs[tid] = A.qd[(size_t)bl * 128 + tid];
    {   // ci rows contiguous in cit (128 float4 each)
        int l = bid & 255;
        if (tid < 128)
            ((float4*)ci0s)[tid] = ((const float4*)(A.cit + ((size_t)b * 512 + l) * 512))[tid];
        else
            ((float4*)ci1s)[tid - 128] = ((const float4*)(A.cit + ((size_t)b * 512 + 256 + l) * 512))[tid - 128];
    }
    __syncthreads();
    if (tid < 8) {
        float a = 0.f, c = 0.f;
#pragma unroll
        for (int d = 0; d < 16; ++d) {
            float qv = qs[tid * 16 + d];
            a += qv * A.uu_in_w[(size_t)(128 + tid * 16 + d) * 128 + 126];
            c += qv * A.uu_in_w[(size_t)(128 + tid * 16 + d) * 128 + 127];
        }
        qkA[tid] = a; qkB[tid] = c;
    }
    __syncthreads();
    {   // scores: thread = (head-pair hg, 4 n at n4 and 4 at n4+256)
        int hg = tid >> 6, n4 = (tid & 63) * 4;
        const float* kp = A.kbaseT + (size_t)b * 128 * 512 + n4;
        float4 acc[2][2] = { { {0,0,0,0}, {0,0,0,0} }, { {0,0,0,0}, {0,0,0,0} } };
#pragma unroll
        for (int hh = 0; hh < 2; ++hh) {
            int h = hg * 2 + hh;
#pragma unroll
            for (int d = 0; d < 16; ++d) {
                int e = h * 16 + d;
                float4 kv0 = *(const float4*)(kp + (size_t)e * 512);
                float4 kv1 = *(const float4*)(kp + (size_t)e * 512 + 256);
                float qv = qs[e];
                acc[hh][0].x += qv * kv0.x; acc[hh][0].y += qv * kv0.y;
                acc[hh][0].z += qv * kv0.z; acc[hh][0].w += qv * kv0.w;
                acc[hh][1].x += qv * kv1.x; acc[hh][1].y += qv * kv1.y;
                acc[hh][1].z += qv * kv1.z; acc[hh][1].w += qv * kv1.w;
            }
        }
#pragma unroll
        for (int hh = 0; hh < 2; ++hh) {
            int h = hg * 2 + hh;
            float qa = qkA[h], qb = qkB[h];
#pragma unroll
            for (int nh = 0; nh < 2; ++nh) {
                int n = n4 + nh * 256;
                float4 s;
                s.x = (((float*)&acc[hh][nh])[0] + ci0s[n]     * qa + ci1s[n]     * qb) * 0.25f;
                s.y = (((float*)&acc[hh][nh])[1] + ci0s[n + 1] * qa + ci1s[n + 1] * qb) * 0.25f;
                s.z = (((float*)&acc[hh][nh])[2] + ci0s[n + 2] * qa + ci1s[n + 2] * qb) * 0.25f;
                s.w = (((float*)&acc[hh][nh])[3] + ci0s[n + 3] * qa + ci1s[n + 3] * qb) * 0.25f;
                *(float4*)(sc + h * 512 + n) = s;
            }
        }
    }
    __syncthreads();
    {   // softmax + ci-weighted sums over 512
        int g = tid >> 5, j = tid & 31;
        float* row = sc + g * 512;
        float mx = -1e30f;
#pragma unroll
        for (int n = j; n < 512; n += 32) mx = fmaxf(mx, row[n]);
#pragma unroll
        for (int off = 16; off; off >>= 1) mx = fmaxf(mx, __shfl_down(mx, off, 32));
        mx = __shfl(mx, 0, 32);
        float s = 0.f, a0 = 0.f, a1 = 0.f;
#pragma unroll
        for (int n = j; n < 512; n += 32) {
            float ev = __expf(row[n] - mx);
            row[n] = ev;
            s += ev; a0 += ev * ci0s[n]; a1 += ev * ci1s[n];
        }
#pragma unroll
        for (int off = 16; off; off >>= 1) {
            s  += __shfl_down(s, off, 32);
            a0 += __shfl_down(a0, off, 32);
            a1 += __shfl_down(a1, off, 32);
        }
        if (j == 0) { den[g] = s; hs0[g] = a0; hs1[g] = a1; }
    }
    __syncthreads();
    {   // V pass partials
        int col = tid & 127, nh = tid >> 7;
        const float* vcol = A.vbase + ((size_t)b * 512 + nh * 256) * 128 + col;
        const float* p = sc + (col >> 4) * 512 + nh * 256;
        float a = 0.f;
#pragma unroll 8
        for (int n = 0; n < 256; ++n) a += p[n] * vcol[(size_t)n * 128];
        vpart[nh * 128 + col] = a;
    }
    __syncthreads();
    if (tid < 128) {
        int g = tid >> 4;
        float sum = vpart[tid] + vpart[128 + tid];
        float wv126 = A.uu_in_w[(size_t)(256 + tid) * 128 + 126];
        float wv127 = A.uu_in_w[(size_t)(256 + tid) * 128 + 127];
        cat[tid] = (sum + hs0[g] * wv126 + hs1[g] * wv127) / den[g];
    }
    __syncthreads();

    // ================= epilogue: y = C @ cat + bias; BN stat atomics =================
    {
        int e = tid & 127, half = tid >> 7;
        const float4* cu4 = (const float4*)(A.Cuu + (size_t)e * 128);
        const float4* ct4 = (const float4*)(A.Cta + (size_t)e * 128);
        const float4* cd4 = (const float4*)(A.Cdu + (size_t)e * 128);
        const float4* x4 = (const float4*)cat;
        float acc = 0.f;
        int c0 = half * 16;
#pragma unroll
        for (int c = c0; c < c0 + 16; ++c) {
            float4 a = cu4[c], bb = ct4[c], d = cd4[c];
            float4 xu = x4[c], xt = x4[32 + c], xd = x4[64 + c];
            acc += a.x * xu.x + a.y * xu.y + a.z * xu.z + a.w * xu.w
                 + bb.x * xt.x + bb.y * xt.y + bb.z * xt.z + bb.w * xt.w
                 + d.x * xd.x + d.y * xd.y + d.z * xd.z + d.w * xd.w;
        }
        vpart[tid] = acc;
        __syncthreads();
        if (tid < 128) {
            float yv = vpart[tid] + vpart[128 + tid] + A.bcomb[tid];
            A.y[(size_t)bl * 128 + tid] = yv;
            atomicAdd(A.gstat + tid, yv);
            atomicAdd(A.gstat + 128 + tid, yv * yv);
        }
    }
}

__global__ __launch_bounds__(256) void bn_apply(
    const float* __restrict__ y, const float* __restrict__ gstat,
    const float* __restrict__ gamma, const float* __restrict__ beta,
    float* __restrict__ out)
{
    int gid = blockIdx.x * 256 + threadIdx.x;      // float4 index, 32768 total
    int c0 = (gid & 31) * 4;
    float4 v = ((const float4*)y)[gid];
    float r[4] = { v.x, v.y, v.z, v.w };
#pragma unroll
    for (int k = 0; k < 4; ++k) {
        int c = c0 + k;
        float mean = gstat[c] * (1.f / 1024.f);
        float var = gstat[128 + c] * (1.f / 1024.f) - mean * mean;
        float inv = rsqrtf(var + 1e-5f);
        r[k] = fmaxf((r[k] - mean) * inv * gamma[c] + beta[c], 0.f);
    }
    float4 ov = { r[0], r[1], r[2], r[3] };
    ((float4*)out)[gid] = ov;
}

extern "C" void kernel_launch(void* const* d_in, const int* in_sizes, int n_in,
                              void* d_out, int out_size, void* d_ws, size_t ws_size,
                              hipStream_t stream)
{
    (void)in_sizes; (void)n_in; (void)out_size; (void)ws_size;
    const float* UUMat    = (const float*)d_in[0];
    const float* DUMat    = (const float*)d_in[1];
    const float* TAMat    = (const float*)d_in[2];
    const float* CIMat    = (const float*)d_in[3];
    const float* uu_in_w  = (const float*)d_in[4];
    const float* uu_in_b  = (const float*)d_in[5];
    const float* uu_out_w = (const float*)d_in[6];
    const float* uu_out_b = (const float*)d_in[7];
    const float* ta_in_w  = (const float*)d_in[8];
    const float* ta_in_b  = (const float*)d_in[9];
    const float* ta_out_w = (const float*)d_in[10];
    const float* ta_out_b = (const float*)d_in[11];
    const float* du_in_w  = (const float*)d_in[12];
    const float* du_in_b  = (const float*)d_in[13];
    const float* du_out_w = (const float*)d_in[14];
    const float* du_out_b = (const float*)d_in[15];
    const float* dim_w    = (const float*)d_in[16];
    const float* dim_b    = (const float*)d_in[17];
    const float* bn_g     = (const float*)d_in[18];
    const float* bn_b     = (const float*)d_in[19];

    const int BL = 1024, BN = 2048;
    float* ws = (float*)d_ws;
    float* gstat  = ws; ws += 256;
    float* cit    = ws; ws += (size_t)4 * 512 * 512;
    float* qd     = ws; ws += (size_t)BL * 128;
    float* kbaseT = ws; ws += (size_t)BN * 128;   // [b][128][512]
    float* vbase  = ws; ws += (size_t)BN * 128;
    float* qta    = ws; ws += (size_t)BL * 128;
    float* ktaT   = ws; ws += (size_t)BL * 128;   // [b][128][256]
    float* vta    = ws; ws += (size_t)BL * 128;
    float* qdu    = ws; ws += (size_t)BL * 128;
    float* kduT   = ws; ws += (size_t)BL * 128;   // [b][128][256]
    float* vdu    = ws; ws += (size_t)BL * 128;
    float* yy     = ws; ws += (size_t)BL * 128;
    float* Cuu    = ws; ws += 128 * 128;
    float* Cta    = ws; ws += 128 * 128;
    float* Cdu    = ws; ws += 128 * 128;
    float* bcomb  = ws; ws += 128;

    PreArgs P;
    P.x[0] = DUMat; P.W[0] = uu_in_w;             P.bia[0] = uu_in_b;       P.out[0] = qd;     P.Kdim[0] = 128; P.transNb[0] = 0;
    P.x[1] = DUMat; P.W[1] = ta_in_w;             P.bia[1] = ta_in_b;       P.out[1] = qta;    P.Kdim[1] = 128; P.transNb[1] = 0;
    P.x[2] = TAMat; P.W[2] = ta_in_w + 128 * 128; P.bia[2] = ta_in_b + 128; P.out[2] = ktaT;   P.Kdim[2] = 128; P.transNb[2] = 256;
    P.x[3] = TAMat; P.W[3] = ta_in_w + 256 * 128; P.bia[3] = ta_in_b + 256; P.out[3] = vta;    P.Kdim[3] = 128; P.transNb[3] = 0;
    P.x[4] = DUMat; P.W[4] = du_in_w;             P.bia[4] = du_in_b;       P.out[4] = qdu;    P.Kdim[4] = 128; P.transNb[4] = 0;
    P.x[5] = DUMat; P.W[5] = du_in_w + 128 * 128; P.bia[5] = du_in_b + 128; P.out[5] = kduT;   P.Kdim[5] = 128; P.transNb[5] = 256;
    P.x[6] = DUMat; P.W[6] = du_in_w + 256 * 128; P.bia[6] = du_in_b + 256; P.out[6] = vdu;    P.Kdim[6] = 128; P.transNb[6] = 0;
    P.x[7] = UUMat; P.W[7] = uu_in_w + 128 * 128; P.bia[7] = uu_in_b + 128; P.out[7] = kbaseT; P.Kdim[7] = 126; P.transNb[7] = 512;
    P.x[8] = UUMat; P.W[8] = uu_in_w + 256 * 128; P.bia[8] = uu_in_b + 256; P.out[8] = vbase;  P.Kdim[8] = 126; P.transNb[8] = 0;
    P.CIMat = CIMat; P.cit = cit;
    P.dim_w = dim_w; P.dim_b = dim_b;
    P.uu_ow = uu_out_w; P.uu_ob = uu_out_b;
    P.ta_ow = ta_out_w; P.ta_ob = ta_out_b;
    P.du_ow = du_out_w; P.du_ob = du_out_b;
    P.Cuu = Cuu; P.Cta = Cta; P.Cdu = Cdu; P.bcomb = bcomb;
    P.gstat = gstat;

    AttnArgs T;
    T.qd = qd; T.kbaseT = kbaseT; T.vbase = vbase; T.cit = cit;
    T.qta = qta; T.ktaT = ktaT; T.vta = vta;
    T.qdu = qdu; T.kduT = kduT; T.vdu = vdu;
    T.uu_in_w = uu_in_w;
    T.Cuu = Cuu; T.Cta = Cta; T.Cdu = Cdu; T.bcomb = bcomb;
    T.y = yy; T.gstat = gstat;

    hipLaunchKernelGGL(pre_fused, dim3(2560), dim3(256), 0, stream, P);
    hipLaunchKernelGGL(attn_epi, dim3(1024), dim3(256), 0, stream, T);
    hipLaunchKernelGGL(bn_apply, dim3(128), dim3(256), 0, stream,
                       yy, gstat, bn_g, bn_b, (float*)d_out);
}

// Round 11
// 194.562 us; speedup vs baseline: 1.1761x; 1.1761x over previous
//
#include <hip/hip_runtime.h>

// B=4, L=256, E=128, H=8, D=16, NU=512, NT=256. All I/O fp32.
// 3 dispatches:
//   1. pre_fused : 9 projections (K transposed) + CI transpose + weight-fold + gstat zero
//   2. attn_epi  : 2 query rows/block, XCD-swizzled (per-XCD working set = one batch):
//                  ta + du + uu attention -> cat in LDS -> epilogue -> spread BN atomics
//   3. bn_apply  : reduce 16 stat copies, normalize + ReLU

struct PreArgs {
    const float* x[9]; const float* W[9]; const float* bia[9]; float* out[9];
    int Kdim[9]; int transNb[9];     // 0 = row-major out; else n-per-b for [b][e][n] layout
    const float* CIMat; float* cit;
    const float* dim_w; const float* dim_b;
    const float* uu_ow; const float* uu_ob;
    const float* ta_ow; const float* ta_ob;
    const float* du_ow; const float* du_ob;
    float* Cuu; float* Cta; float* Cdu; float* bcomb;
    float* gstat;                    // 16 copies x 256 floats (zeroed here)
};

// tasks: [0,1408) proj (8 rows each), [1408,2432) CI transpose, [2432,2560) fold
__global__ __launch_bounds__(256) void pre_fused(PreArgs A)
{
    __shared__ __align__(16) float smem[1056];
    int bid = blockIdx.x, tid = threadIdx.x;
    if (bid == 0)
        for (int i = tid; i < 16 * 256; i += 256) A.gstat[i] = 0.f;

    if (bid < 1408) {
        int task, mblk;
        if (bid < 896) { task = bid >> 7; mblk = bid & 127; }
        else { int r = bid - 896; task = 7 + (r >> 8); mblk = r & 255; }
        int Kd = A.Kdim[task];
        const float* x = A.x[task];
        int m0 = mblk * 8;
        if (Kd == 128) {
            ((float4*)smem)[tid] = ((const float4*)(x + (size_t)m0 * 128))[tid];
        } else {
            for (int i = tid; i < 1024; i += 256) {
                int r = i >> 7, c = i & 127;
                smem[i] = (c < Kd) ? x[(size_t)(m0 + r) * Kd + c] : 0.f;
            }
        }
        __syncthreads();
        int e = tid & 127, half = tid >> 7;
        const float4* w4 = (const float4*)(A.W[task] + (size_t)e * 128);
        const float4* xs4 = (const float4*)smem + half * 4 * 32;
        float acc[4];
        float bv = A.bia[task][e];
#pragma unroll
        for (int r = 0; r < 4; ++r) acc[r] = bv;
#pragma unroll 8
        for (int c = 0; c < 32; ++c) {
            float4 w = w4[c];
#pragma unroll
            for (int r = 0; r < 4; ++r) {
                float4 xv = xs4[r * 32 + c];
                acc[r] += w.x * xv.x + w.y * xv.y + w.z * xv.z + w.w * xv.w;
            }
        }
        int nb = A.transNb[task];
        float* op = A.out[task];
        if (nb == 0) {
#pragma unroll
            for (int r = 0; r < 4; ++r)
                op[(size_t)(m0 + half * 4 + r) * 128 + e] = acc[r];
        } else {
            int b = m0 / nb, nloc = m0 - b * nb;
            float* o = op + ((size_t)b * 128 + e) * nb + nloc + half * 4;
            float4 v = { acc[0], acc[1], acc[2], acc[3] };
            *(float4*)o = v;
        }
    } else if (bid < 2432) {
        int tb = bid - 1408;
        int b = tb >> 8, tt = tb & 255;
        int n0 = (tt >> 4) * 32, c0 = (tt & 15) * 32;
        float (*tile)[33] = (float(*)[33])smem;
        int tx = tid & 31, ty = tid >> 5;   // 32 x 8
        const float* src = A.CIMat + (size_t)b * 262144;
        float* dst = A.cit + (size_t)b * 262144;
#pragma unroll
        for (int i = ty; i < 32; i += 8)
            tile[i][tx] = src[(size_t)(n0 + i) * 512 + c0 + tx];
        __syncthreads();
#pragma unroll
        for (int i = ty; i < 32; i += 8)
            dst[(size_t)(c0 + i) * 512 + n0 + tx] = tile[tx][i];
    } else {
        float* ds = smem;
        float* red = smem + 384;
        int e = bid - 2432, k = tid;
        if (k < 128) {
            ds[k]       = A.dim_w[(size_t)e * 384 + k];
            ds[128 + k] = A.dim_w[(size_t)e * 384 + 128 + k];
            ds[256 + k] = A.dim_w[(size_t)e * 384 + 256 + k];
        }
        __syncthreads();
        if (k < 128) {
            float cu = 0.f, ct = 0.f, cd = 0.f;
#pragma unroll 4
            for (int j = 0; j < 128; ++j) {
                cu += ds[j]       * A.uu_ow[(size_t)j * 128 + k];
                ct += ds[128 + j] * A.ta_ow[(size_t)j * 128 + k];
                cd += ds[256 + j] * A.du_ow[(size_t)j * 128 + k];
            }
            A.Cuu[(size_t)e * 128 + k] = cu;
            A.Cta[(size_t)e * 128 + k] = ct;
            A.Cdu[(size_t)e * 128 + k] = cd;
            red[k] = ds[k] * A.uu_ob[k] + ds[128 + k] * A.ta_ob[k] + ds[256 + k] * A.du_ob[k];
        }
        __syncthreads();
        for (int off = 64; off; off >>= 1) {
            if (k < off) red[k] += red[k + off];
            __syncthreads();
        }
        if (k == 0) A.bcomb[e] = A.dim_b[e] + red[0];
    }
}

struct AttnArgs {
    const float* qd; const float* kbaseT; const float* vbase; const float* cit;
    const float* qta; const float* ktaT; const float* vta;
    const float* qdu; const float* kduT; const float* vdu;
    const float* uu_in_w;
    const float* Cuu; const float* Cta; const float* Cdu; const float* bcomb;
    float* y; float* gstat;
};

// 2 query rows per block, 512 blocks. XCD swizzle: xcd = bid&7 -> b = xcd>>1.
// LDS (floats): qs 256 | sc(float2) 8192 | ci0 1024 | ci1 1024 | cat 768 | vpart 512 | misc 80
__global__ __launch_bounds__(256) void attn_epi(AttnArgs A)
{
    __shared__ __align__(16) float smem[11856];   // 47.4 KB
    int bid = blockIdx.x, tid = threadIdx.x;
    int xcd = bid & 7, local = bid >> 3;          // consecutive bids round-robin XCDs
    int b = xcd >> 1;
    int l0 = ((xcd & 1) * 64 + local) * 2;
    int bl0 = b * 256 + l0;
    float*  qs    = smem;            // [l][128]
    float2* sc2   = (float2*)(smem + 256);   // [h][n] -> (row0,row1)
    float*  ci0s  = smem + 8448;     // [l*512 + n]
    float*  ci1s  = smem + 9472;
    float*  cat   = smem + 10496;    // [l][384]
    float*  vpart = smem + 11264;    // 512
    float*  den   = smem + 11776;    // [h*2+l]
    float*  hs0   = den + 16;
    float*  hs1   = hs0 + 16;
    float*  qkA   = hs1 + 16;        // [h*2+l]
    float*  qkB   = qkA + 16;

    // ================= ta and du stages (N=256) =================
    for (int kind = 0; kind < 2; ++kind) {
        const float* q  = kind ? A.qdu  : A.qta;
        const float* kT = kind ? A.kduT : A.ktaT;
        const float* v  = kind ? A.vdu  : A.vta;
        int catoff = 128 + kind * 128;
        __syncthreads();
        { int l = tid >> 7, d = tid & 127; qs[l * 128 + d] = q[(size_t)(bl0 + l) * 128 + d]; }
        __syncthreads();
        {   // scores: thread = (head-pair hg, 4 consecutive n); coalesced float4 kT reads
            int hg = tid >> 6, n4 = (tid & 63) * 4;
            const float* kp = kT + (size_t)b * 128 * 256 + n4;
            float acc[2][2][4];   // [l][hh][j]
#pragma unroll
            for (int l = 0; l < 2; ++l)
#pragma unroll
                for (int hh = 0; hh < 2; ++hh)
#pragma unroll
                    for (int j = 0; j < 4; ++j) acc[l][hh][j] = 0.f;
#pragma unroll
            for (int hh = 0; hh < 2; ++hh) {
                int h = hg * 2 + hh;
#pragma unroll
                for (int d = 0; d < 16; ++d) {
                    int e = h * 16 + d;
                    float4 kv = *(const float4*)(kp + (size_t)e * 256);
                    float q0 = qs[e], q1 = qs[128 + e];
                    acc[0][hh][0] += q0 * kv.x; acc[0][hh][1] += q0 * kv.y;
                    acc[0][hh][2] += q0 * kv.z; acc[0][hh][3] += q0 * kv.w;
                    acc[1][hh][0] += q1 * kv.x; acc[1][hh][1] += q1 * kv.y;
                    acc[1][hh][2] += q1 * kv.z; acc[1][hh][3] += q1 * kv.w;
                }
            }
#pragma unroll
            for (int hh = 0; hh < 2; ++hh) {
                int h = hg * 2 + hh;
#pragma unroll
                for (int j = 0; j < 4; ++j) {
                    float2 s = { acc[0][hh][j] * 0.25f, acc[1][hh][j] * 0.25f };
                    sc2[h * 256 + n4 + j] = s;
                }
            }
        }
        __syncthreads();
        {   // softmax: 8 head-groups x 32 lanes, both rows via float2
            int g = tid >> 5, j = tid & 31;
            float2* row = sc2 + g * 256;
            float2 mx = { -1e30f, -1e30f };
#pragma unroll
            for (int n = j; n < 256; n += 32) {
                float2 vv = row[n];
                mx.x = fmaxf(mx.x, vv.x); mx.y = fmaxf(mx.y, vv.y);
            }
#pragma unroll
            for (int off = 16; off; off >>= 1) {
                mx.x = fmaxf(mx.x, __shfl_down(mx.x, off, 32));
                mx.y = fmaxf(mx.y, __shfl_down(mx.y, off, 32));
            }
            mx.x = __shfl(mx.x, 0, 32); mx.y = __shfl(mx.y, 0, 32);
            float2 s = { 0.f, 0.f };
#pragma unroll
            for (int n = j; n < 256; n += 32) {
                float2 vv = row[n];
                vv.x = __expf(vv.x - mx.x); vv.y = __expf(vv.y - mx.y);
                row[n] = vv;
                s.x += vv.x; s.y += vv.y;
            }
#pragma unroll
            for (int off = 16; off; off >>= 1) {
                s.x += __shfl_down(s.x, off, 32); s.y += __shfl_down(s.y, off, 32);
            }
            if (j == 0) { den[g * 2] = s.x; den[g * 2 + 1] = s.y; }
        }
        __syncthreads();
        {   // V pass partials: (col, n-half)
            int col = tid & 127, nh = tid >> 7;
            const float* vcol = v + ((size_t)b * 256 + nh * 128) * 128 + col;
            const float2* p = sc2 + (col >> 4) * 256 + nh * 128;
            float a0 = 0.f, a1 = 0.f;
#pragma unroll 8
            for (int n = 0; n < 128; ++n) {
                float vv = vcol[(size_t)n * 128];
                float2 pp = p[n];
                a0 += pp.x * vv; a1 += pp.y * vv;
            }
            vpart[nh * 256 + col * 2]     = a0;
            vpart[nh * 256 + col * 2 + 1] = a1;
        }
        __syncthreads();
        {
            int col = tid & 127, l = tid >> 7, h = col >> 4;
            float sum = vpart[col * 2 + l] + vpart[256 + col * 2 + l];
            cat[l * 384 + catoff + col] = sum / den[h * 2 + l];
        }
    }

    // ================= uu stage (N=512, rank-2 ci correction) =================
    __syncthreads();
    { int l = tid >> 7, d = tid & 127; qs[l * 128 + d] = A.qd[(size_t)(bl0 + l) * 128 + d]; }
    {   // 2 cit rows per tensor, contiguous: 1024 floats = 256 float4 each
        const float4* s0 = (const float4*)(A.cit + ((size_t)b * 512 + l0) * 512);
        const float4* s1 = (const float4*)(A.cit + ((size_t)b * 512 + 256 + l0) * 512);
        ((float4*)ci0s)[tid] = s0[tid];
        ((float4*)ci1s)[tid] = s1[tid];
    }
    __syncthreads();
    if (tid < 16) {
        int h = tid >> 1, l = tid & 1;
        float a = 0.f, c = 0.f;
#pragma unroll
        for (int d = 0; d < 16; ++d) {
            float qv = qs[l * 128 + h * 16 + d];
            a += qv * A.uu_in_w[(size_t)(128 + h * 16 + d) * 128 + 126];
            c += qv * A.uu_in_w[(size_t)(128 + h * 16 + d) * 128 + 127];
        }
        qkA[tid] = a; qkB[tid] = c;
    }
    __syncthreads();
    {   // scores: thread = (head-pair hg, 4 n at n4 and n4+256); float4 reads
        int hg = tid >> 6, n4 = (tid & 63) * 4;
        const float* kp = A.kbaseT + (size_t)b * 128 * 512 + n4;
        float acc[2][2][2][4];   // [nh][l][hh][j]
#pragma unroll
        for (int nh = 0; nh < 2; ++nh)
#pragma unroll
            for (int l = 0; l < 2; ++l)
#pragma unroll
                for (int hh = 0; hh < 2; ++hh)
#pragma unroll
                    for (int j = 0; j < 4; ++j) acc[nh][l][hh][j] = 0.f;
#pragma unroll
        for (int hh = 0; hh < 2; ++hh) {
            int h = hg * 2 + hh;
#pragma unroll
            for (int d = 0; d < 16; ++d) {
                int e = h * 16 + d;
                float4 kv0 = *(const float4*)(kp + (size_t)e * 512);
                float4 kv1 = *(const float4*)(kp + (size_t)e * 512 + 256);
                float q0 = qs[e], q1 = qs[128 + e];
                acc[0][0][hh][0] += q0 * kv0.x; acc[0][0][hh][1] += q0 * kv0.y;
                acc[0][0][hh][2] += q0 * kv0.z; acc[0][0][hh][3] += q0 * kv0.w;
                acc[0][1][hh][0] += q1 * kv0.x; acc[0][1][hh][1] += q1 * kv0.y;
                acc[0][1][hh][2] += q1 * kv0.z; acc[0][1][hh][3] += q1 * kv0.w;
                acc[1][0][hh][0] += q0 * kv1.x; acc[1][0][hh][1] += q0 * kv1.y;
                acc[1][0][hh][2] += q0 * kv1.z; acc[1][0][hh][3] += q0 * kv1.w;
                acc[1][1][hh][0] += q1 * kv1.x; acc[1][1][hh][1] += q1 * kv1.y;
                acc[1][1][hh][2] += q1 * kv1.z; acc[1][1][hh][3] += q1 * kv1.w;
            }
        }
#pragma unroll
        for (int nh = 0; nh < 2; ++nh) {
#pragma unroll
            for (int hh = 0; hh < 2; ++hh) {
                int h = hg * 2 + hh;
                float qa0 = qkA[h * 2], qa1 = qkA[h * 2 + 1];
                float qb0 = qkB[h * 2], qb1 = qkB[h * 2 + 1];
#pragma unroll
                for (int j = 0; j < 4; ++j) {
                    int n = n4 + nh * 256 + j;
                    float c0l0 = ci0s[n], c0l1 = ci0s[512 + n];
                    float c1l0 = ci1s[n], c1l1 = ci1s[512 + n];
                    float2 s;
                    s.x = (acc[nh][0][hh][j] + c0l0 * qa0 + c1l0 * qb0) * 0.25f;
                    s.y = (acc[nh][1][hh][j] + c0l1 * qa1 + c1l1 * qb1) * 0.25f;
                    sc2[h * 512 + n] = s;
                }
            }
        }
    }
    __syncthreads();
    {   // softmax + ci-weighted sums over 512
        int g = tid >> 5, j = tid & 31;
        float2* row = sc2 + g * 512;
        float2 mx = { -1e30f, -1e30f };
#pragma unroll
        for (int n = j; n < 512; n += 32) {
            float2 vv = row[n];
            mx.x = fmaxf(mx.x, vv.x); mx.y = fmaxf(mx.y, vv.y);
        }
#pragma unroll
        for (int off = 16; off; off >>= 1) {
            mx.x = fmaxf(mx.x, __shfl_down(mx.x, off, 32));
            mx.y = fmaxf(mx.y, __shfl_down(mx.y, off, 32));
        }
        mx.x = __shfl(mx.x, 0, 32); mx.y = __shfl(mx.y, 0, 32);
        float2 s = { 0.f, 0.f }, a0 = { 0.f, 0.f }, a1 = { 0.f, 0.f };
#pragma unroll
        for (int n = j; n < 512; n += 32) {
            float2 vv = row[n];
            vv.x = __expf(vv.x - mx.x); vv.y = __expf(vv.y - mx.y);
            row[n] = vv;
            s.x += vv.x; s.y += vv.y;
            a0.x += vv.x * ci0s[n]; a0.y += vv.y * ci0s[512 + n];
            a1.x += vv.x * ci1s[n]; a1.y += vv.y * ci1s[512 + n];
        }
#pragma unroll
        for (int off = 16; off; off >>= 1) {
            s.x  += __shfl_down(s.x, off, 32);  s.y  += __shfl_down(s.y, off, 32);
            a0.x += __shfl_down(a0.x, off, 32); a0.y += __shfl_down(a0.y, off, 32);
            a1.x += __shfl_down(a1.x, off, 32); a1.y += __shfl_down(a1.y, off, 32);
        }
        if (j == 0) {
            den[g * 2] = s.x;  den[g * 2 + 1] = s.y;
            hs0[g * 2] = a0.x; hs0[g * 2 + 1] = a0.y;
            hs1[g * 2] = a1.x; hs1[g * 2 + 1] = a1.y;
        }
    }
    __syncthreads();
    {   // V pass partials
        int col = tid & 127, nh = tid >> 7;
        const float* vcol = A.vbase + ((size_t)b * 512 + nh * 256) * 128 + col;
        const float2* p = sc2 + (col >> 4) * 512 + nh * 256;
        float a0 = 0.f, a1 = 0.f;
#pragma unroll 8
        for (int n = 0; n < 256; ++n) {
            float vv = vcol[(size_t)n * 128];
            float2 pp = p[n];
            a0 += pp.x * vv; a1 += pp.y * vv;
        }
        vpart[nh * 256 + col * 2]     = a0;
        vpart[nh * 256 + col * 2 + 1] = a1;
    }
    __syncthreads();
    {
        int col = tid & 127, l = tid >> 7, g = (col >> 4) * 2 + l;
        float sum = vpart[col * 2 + l] + vpart[256 + col * 2 + l];
        float wv126 = A.uu_in_w[(size_t)(256 + col) * 128 + 126];
        float wv127 = A.uu_in_w[(size_t)(256 + col) * 128 + 127];
        cat[l * 384 + col] = (sum + hs0[g] * wv126 + hs1[g] * wv127) / den[g];
    }
    __syncthreads();

    // ================= epilogue: y = C @ cat + bias; spread BN stat atomics =================
    {
        int e = tid & 127, l = tid >> 7;
        const float4* cu4 = (const float4*)(A.Cuu + (size_t)e * 128);
        const float4* ct4 = (const float4*)(A.Cta + (size_t)e * 128);
        const float4* cd4 = (const float4*)(A.Cdu + (size_t)e * 128);
        const float4* x4 = (const float4*)(cat + l * 384);
        float acc = A.bcomb[e];
#pragma unroll 4
        for (int c = 0; c < 32; ++c) {
            float4 a = cu4[c], bb = ct4[c], d = cd4[c];
            float4 xu = x4[c], xt = x4[32 + c], xd = x4[64 + c];
            acc += a.x * xu.x + a.y * xu.y + a.z * xu.z + a.w * xu.w
                 + bb.x * xt.x + bb.y * xt.y + bb.z * xt.z + bb.w * xt.w
                 + d.x * xd.x + d.y * xd.y + d.z * xd.z + d.w * xd.w;
        }
        A.y[(size_t)(bl0 + l) * 128 + e] = acc;
        vpart[tid] = acc;
        __syncthreads();
        if (tid < 128) {
            float* gs = A.gstat + (bid & 15) * 256;    // 16 spread copies
            atomicAdd(gs + tid, vpart[tid] + vpart[tid + 128]);
            float v0 = vpart[tid], v1 = vpart[tid + 128];
            atomicAdd(gs + 128 + tid, v0 * v0 + v1 * v1);
        }
    }
}

__global__ __launch_bounds__(256) void bn_apply(
    const float* __restrict__ y, const float* __restrict__ gstat,
    const float* __restrict__ gamma, const float* __restrict__ beta,
    float* __restrict__ out)
{
    int gid = blockIdx.x * 256 + threadIdx.x;      // float4 index, 32768 total
    int c0 = (gid & 31) * 4;
    float4 v = ((const float4*)y)[gid];
    float r[4] = { v.x, v.y, v.z, v.w };
#pragma unroll
    for (int k = 0; k < 4; ++k) {
        int c = c0 + k;
        float s = 0.f, s2 = 0.f;
#pragma unroll
        for (int cp = 0; cp < 16; ++cp) {
            s  += gstat[cp * 256 + c];
            s2 += gstat[cp * 256 + 128 + c];
        }
        float mean = s * (1.f / 1024.f);
        float var = s2 * (1.f / 1024.f) - mean * mean;
        float inv = rsqrtf(var + 1e-5f);
        r[k] = fmaxf((r[k] - mean) * inv * gamma[c] + beta[c], 0.f);
    }
    float4 ov = { r[0], r[1], r[2], r[3] };
    ((float4*)out)[gid] = ov;
}

extern "C" void kernel_launch(void* const* d_in, const int* in_sizes, int n_in,
                              void* d_out, int out_size, void* d_ws, size_t ws_size,
                              hipStream_t stream)
{
    (void)in_sizes; (void)n_in; (void)out_size; (void)ws_size;
    const float* UUMat    = (const float*)d_in[0];
    const float* DUMat    = (const float*)d_in[1];
    const float* TAMat    = (const float*)d_in[2];
    const float* CIMat    = (const float*)d_in[3];
    const float* uu_in_w  = (const float*)d_in[4];
    const float* uu_in_b  = (const float*)d_in[5];
    const float* uu_out_w = (const float*)d_in[6];
    const float* uu_out_b = (const float*)d_in[7];
    const float* ta_in_w  = (const float*)d_in[8];
    const float* ta_in_b  = (const float*)d_in[9];
    const float* ta_out_w = (const float*)d_in[10];
    const float* ta_out_b = (const float*)d_in[11];
    const float* du_in_w  = (const float*)d_in[12];
    const float* du_in_b  = (const float*)d_in[13];
    const float* du_out_w = (const float*)d_in[14];
    const float* du_out_b = (const float*)d_in[15];
    const float* dim_w    = (const float*)d_in[16];
    const float* dim_b    = (const float*)d_in[17];
    const float* bn_g     = (const float*)d_in[18];
    const float* bn_b     = (const float*)d_in[19];

    const int BL = 1024, BN = 2048;
    float* ws = (float*)d_ws;
    float* gstat  = ws; ws += 16 * 256;
    float* cit    = ws; ws += (size_t)4 * 512 * 512;
    float* qd     = ws; ws += (size_t)BL * 128;
    float* kbaseT = ws; ws += (size_t)BN * 128;   // [b][128][512]
    float* vbase  = ws; ws += (size_t)BN * 128;
    float* qta    = ws; ws += (size_t)BL * 128;
    float* ktaT   = ws; ws += (size_t)BL * 128;   // [b][128][256]
    float* vta    = ws; ws += (size_t)BL * 128;
    float* qdu    = ws; ws += (size_t)BL * 128;
    float* kduT   = ws; ws += (size_t)BL * 128;   // [b][128][256]
    float* vdu    = ws; ws += (size_t)BL * 128;
    float* yy     = ws; ws += (size_t)BL * 128;
    float* Cuu    = ws; ws += 128 * 128;
    float* Cta    = ws; ws += 128 * 128;
    float* Cdu    = ws; ws += 128 * 128;
    float* bcomb  = ws; ws += 128;

    PreArgs P;
    P.x[0] = DUMat; P.W[0] = uu_in_w;             P.bia[0] = uu_in_b;       P.out[0] = qd;     P.Kdim[0] = 128; P.transNb[0] = 0;
    P.x[1] = DUMat; P.W[1] = ta_in_w;             P.bia[1] = ta_in_b;       P.out[1] = qta;    P.Kdim[1] = 128; P.transNb[1] = 0;
    P.x[2] = TAMat; P.W[2] = ta_in_w + 128 * 128; P.bia[2] = ta_in_b + 128; P.out[2] = ktaT;   P.Kdim[2] = 128; P.transNb[2] = 256;
    P.x[3] = TAMat; P.W[3] = ta_in_w + 256 * 128; P.bia[3] = ta_in_b + 256; P.out[3] = vta;    P.Kdim[3] = 128; P.transNb[3] = 0;
    P.x[4] = DUMat; P.W[4] = du_in_w;             P.bia[4] = du_in_b;       P.out[4] = qdu;    P.Kdim[4] = 128; P.transNb[4] = 0;
    P.x[5] = DUMat; P.W[5] = du_in_w + 128 * 128; P.bia[5] = du_in_b + 128; P.out[5] = kduT;   P.Kdim[5] = 128; P.transNb[5] = 256;
    P.x[6] = DUMat; P.W[6] = du_in_w + 256 * 128; P.bia[6] = du_in_b + 256; P.out[6] = vdu;    P.Kdim[6] = 128; P.transNb[6] = 0;
    P.x[7] = UUMat; P.W[7] = uu_in_w + 128 * 128; P.bia[7] = uu_in_b + 128; P.out[7] = kbaseT; P.Kdim[7] = 126; P.transNb[7] = 512;
    P.x[8] = UUMat; P.W[8] = uu_in_w + 256 * 128; P.bia[8] = uu_in_b + 256; P.out[8] = vbase;  P.Kdim[8] = 126; P.transNb[8] = 0;
    P.CIMat = CIMat; P.cit = cit;
    P.dim_w = dim_w; P.dim_b = dim_b;
    P.uu_ow = uu_out_w; P.uu_ob = uu_out_b;
    P.ta_ow = ta_out_w; P.ta_ob = ta_out_b;
    P.du_ow = du_out_w; P.du_ob = du_out_b;
    P.Cuu = Cuu; P.Cta = Cta; P.Cdu = Cdu; P.bcomb = bcomb;
    P.gstat = gstat;

    AttnArgs T;
    T.qd = qd; T.kbaseT = kbaseT; T.vbase = vbase; T.cit = cit;
    T.qta = qta; T.ktaT = ktaT; T.vta = vta;
    T.qdu = qdu; T.kduT = kduT; T.vdu = vdu;
    T.uu_in_w = uu_in_w;
    T.Cuu = Cuu; T.Cta = Cta; T.Cdu = Cdu; T.bcomb = bcomb;
    T.y = yy; T.gstat = gstat;

    hipLaunchKernelGGL(pre_fused, dim3(2560), dim3(256), 0, stream, P);
    hipLaunchKernelGGL(attn_epi, dim3(512), dim3(256), 0, stream, T);
    hipLaunchKernelGGL(bn_apply, dim3(128), dim3(256), 0, stream,
                       yy, gstat, bn_g, bn_b, (float*)d_out);
}

// Round 12
// 184.711 us; speedup vs baseline: 1.2388x; 1.0533x over previous
//
#include <hip/hip_runtime.h>

// B=4, L=256, E=128, H=8, D=16, NU=512, NT=256. All I/O fp32.
// 4 dispatches:
//   1. pre_fused : 9 projections (16 rows/block, K transposed) + CI transpose + fold + gstat zero
//   2. attn      : head-split tasks (ta/du: 2h x 8r over N=256; uu: 2h x 2r over N=512),
//                  XCD-swizzled so each XCD works on one batch (L2-resident K/V/cit)
//   3. epilogue  : y = Cuu@ouu + Cta@ota + Cdu@odu + bias; spread BN stat atomics
//   4. bn_apply  : reduce 16 stat copies, normalize + ReLU

struct PreArgs {
    const float* x[9]; const float* W[9]; const float* bia[9]; float* out[9];
    int Kdim[9]; int transNb[9];     // 0 = row-major out; else n-per-b for [b][e][n] layout
    const float* CIMat; float* cit;
    const float* dim_w; const float* dim_b;
    const float* uu_ow; const float* uu_ob;
    const float* ta_ow; const float* ta_ob;
    const float* du_ow; const float* du_ob;
    float* Cuu; float* Cta; float* Cdu; float* bcomb;
    float* gstat;                    // 16 copies x 256 floats (zeroed here)
};

// tasks: [0,704) proj (16 rows each), [704,1728) CI transpose, [1728,1856) fold
__global__ __launch_bounds__(256) void pre_fused(PreArgs A)
{
    __shared__ __align__(16) float smem[2048];
    int bid = blockIdx.x, tid = threadIdx.x;
    if (bid == 0)
        for (int i = tid; i < 16 * 256; i += 256) A.gstat[i] = 0.f;

    if (bid < 704) {
        // ---- projection: 16 rows per block ----
        int task, mblk;
        if (bid < 448) { task = bid >> 6; mblk = bid & 63; }
        else { int r = bid - 448; task = 7 + (r >> 7); mblk = r & 127; }
        int Kd = A.Kdim[task];
        const float* x = A.x[task];
        int m0 = mblk * 16;
        if (Kd == 128) {
            const float4* x4 = (const float4*)(x + (size_t)m0 * 128);
            ((float4*)smem)[tid] = x4[tid];
            ((float4*)smem)[tid + 256] = x4[tid + 256];
        } else {
            for (int i = tid; i < 2048; i += 256) {
                int r = i >> 7, c = i & 127;
                smem[i] = (c < Kd) ? x[(size_t)(m0 + r) * Kd + c] : 0.f;
            }
        }
        __syncthreads();
        int e = tid & 127, half = tid >> 7;
        int r0 = half * 8;
        const float4* w4 = (const float4*)(A.W[task] + (size_t)e * 128);
        const float4* xs4 = (const float4*)smem;
        float acc[8];
        float bv = A.bia[task][e];
#pragma unroll
        for (int r = 0; r < 8; ++r) acc[r] = bv;
#pragma unroll 8
        for (int c = 0; c < 32; ++c) {
            float4 w = w4[c];
#pragma unroll
            for (int r = 0; r < 8; ++r) {
                float4 xv = xs4[(r0 + r) * 32 + c];
                acc[r] += w.x * xv.x + w.y * xv.y + w.z * xv.z + w.w * xv.w;
            }
        }
        int nb = A.transNb[task];
        float* op = A.out[task];
        if (nb == 0) {
#pragma unroll
            for (int r = 0; r < 8; ++r)
                op[(size_t)(m0 + r0 + r) * 128 + e] = acc[r];
        } else {
            int b = m0 / nb, nloc = m0 - b * nb;
            float* o = op + ((size_t)b * 128 + e) * nb + nloc + r0;
            float4 v0 = { acc[0], acc[1], acc[2], acc[3] };
            float4 v1 = { acc[4], acc[5], acc[6], acc[7] };
            *(float4*)o = v0;
            *(float4*)(o + 4) = v1;
        }
    } else if (bid < 1728) {
        // ---- CI transpose ----
        int tb = bid - 704;
        int b = tb >> 8, tt = tb & 255;
        int n0 = (tt >> 4) * 32, c0 = (tt & 15) * 32;
        float (*tile)[33] = (float(*)[33])smem;
        int tx = tid & 31, ty = tid >> 5;   // 32 x 8
        const float* src = A.CIMat + (size_t)b * 262144;
        float* dst = A.cit + (size_t)b * 262144;
#pragma unroll
        for (int i = ty; i < 32; i += 8)
            tile[i][tx] = src[(size_t)(n0 + i) * 512 + c0 + tx];
        __syncthreads();
#pragma unroll
        for (int i = ty; i < 32; i += 8)
            dst[(size_t)(c0 + i) * 512 + n0 + tx] = tile[tx][i];
    } else {
        // ---- fold out-projections into dim projection ----
        float* ds = smem;
        float* red = smem + 384;
        int e = bid - 1728, k = tid;
        if (k < 128) {
            ds[k]       = A.dim_w[(size_t)e * 384 + k];
            ds[128 + k] = A.dim_w[(size_t)e * 384 + 128 + k];
            ds[256 + k] = A.dim_w[(size_t)e * 384 + 256 + k];
        }
        __syncthreads();
        if (k < 128) {
            float cu = 0.f, ct = 0.f, cd = 0.f;
#pragma unroll 4
            for (int j = 0; j < 128; ++j) {
                cu += ds[j]       * A.uu_ow[(size_t)j * 128 + k];
                ct += ds[128 + j] * A.ta_ow[(size_t)j * 128 + k];
                cd += ds[256 + j] * A.du_ow[(size_t)j * 128 + k];
            }
            A.Cuu[(size_t)e * 128 + k] = cu;
            A.Cta[(size_t)e * 128 + k] = ct;
            A.Cdu[(size_t)e * 128 + k] = cd;
            red[k] = ds[k] * A.uu_ob[k] + ds[128 + k] * A.ta_ob[k] + ds[256 + k] * A.du_ob[k];
        }
        __syncthreads();
        for (int off = 64; off; off >>= 1) {
            if (k < off) red[k] += red[k + off];
            __syncthreads();
        }
        if (k == 0) A.bcomb[e] = A.dim_b[e] + red[0];
    }
}

struct AttnArgs {
    const float* qd; const float* kbaseT; const float* vbase; const float* cit;
    const float* qta; const float* ktaT; const float* vta;
    const float* qdu; const float* kduT; const float* vdu;
    const float* uu_in_w;
    float* ouu; float* ota; float* odu;
};

// 3072 blocks. XCD swizzle: xcd = bid&7 handles batch b = xcd>>1.
// Per-(b,half): 384 tasks = 128 ta (2h x 8r) + 128 du + ... (t = half*384 + idx in [0,768)):
//   t<128: ta, t<256: du, t>=256: uu (2h x 2r, 512 tasks per b total)
__global__ __launch_bounds__(256) void attn_kernel(AttnArgs A)
{
    __shared__ __align__(16) float smem[4608];   // 18.4 KB
    int bid = blockIdx.x, tid = threadIdx.x;
    int xcd = bid & 7, idx = bid >> 3;           // idx 0..383
    int b = xcd >> 1, half = xcd & 1;
    int t = half * 384 + idx;                    // 0..767

    if (t < 256) {
        // ================= ta / du: 2 heads x 8 rows, N=256 =================
        int kind = t >> 7;                       // 0 = ta, 1 = du
        int u = t & 127;
        int hg = u >> 5, lt = u & 31;
        int l0 = lt * 8, bl0 = b * 256 + l0;
        const float* q  = kind ? A.qdu  : A.qta;
        const float* kT = kind ? A.kduT : A.ktaT;
        const float* v  = kind ? A.vdu  : A.vta;
        float* o        = kind ? A.odu  : A.ota;
        float* qs  = smem;          // 256 [l][d]
        float* sc  = smem + 256;    // 16*256 [(hl*8+l)][n]
        float* den = smem + 4352;   // 16
        {
            int l = tid >> 5, d = tid & 31;
            qs[l * 32 + d] = q[(size_t)(bl0 + l) * 128 + hg * 32 + d];
        }
        __syncthreads();
        {   // scores: lane <-> key n, coalesced kT reads
            int n = tid;
            const float* kp = kT + ((size_t)b * 128 + hg * 32) * 256 + n;
            float acc[8][2];
#pragma unroll
            for (int l = 0; l < 8; ++l) { acc[l][0] = 0.f; acc[l][1] = 0.f; }
#pragma unroll 8
            for (int d = 0; d < 32; ++d) {
                float kv = kp[(size_t)d * 256];
                int hl = d >> 4;
#pragma unroll
                for (int l = 0; l < 8; ++l) acc[l][hl] += qs[l * 32 + d] * kv;
            }
#pragma unroll
            for (int hl = 0; hl < 2; ++hl)
#pragma unroll
                for (int l = 0; l < 8; ++l)
                    sc[(hl * 8 + l) * 256 + n] = acc[l][hl] * 0.25f;
        }
        __syncthreads();
        {   // softmax: 16 groups x 16 lanes
            int g = tid >> 4, j = tid & 15;
            float* row = sc + g * 256;
            float mx = -1e30f;
#pragma unroll 4
            for (int n = j; n < 256; n += 16) mx = fmaxf(mx, row[n]);
#pragma unroll
            for (int off = 8; off; off >>= 1) mx = fmaxf(mx, __shfl_down(mx, off, 16));
            mx = __shfl(mx, 0, 16);
            float s = 0.f;
#pragma unroll 4
            for (int n = j; n < 256; n += 16) {
                float ev = __expf(row[n] - mx);
                row[n] = ev; s += ev;
            }
#pragma unroll
            for (int off = 8; off; off >>= 1) s += __shfl_down(s, off, 16);
            if (j == 0) den[g] = s;
        }
        __syncthreads();
        {   // V pass
            int col = tid & 31, l = tid >> 5;
            int colglob = hg * 32 + col;
            int g = (col >> 4) * 8 + l;
            const float* vcol = v + (size_t)b * 256 * 128 + colglob;
            const float* p = sc + g * 256;
            float acc = 0.f;
#pragma unroll 8
            for (int n = 0; n < 256; ++n) acc += p[n] * vcol[(size_t)n * 128];
            o[(size_t)(bl0 + l) * 128 + colglob] = acc / den[g];
        }
    } else {
        // ================= uu: 2 heads x 2 rows, N=512, rank-2 ci =================
        int u = t - 256;                         // 0..511
        int hg = u >> 7, lt = u & 127;
        int l0 = lt * 2, bl0 = b * 256 + l0;
        float* qs    = smem;          // 64 [l][d]
        float* sc    = smem + 64;     // 4*512 [(hl*2+l)][n]
        float* ci0s  = smem + 2112;   // 2*512 [l][n]
        float* ci1s  = smem + 3136;   // 2*512
        float* vpart = smem + 4160;   // 256 [nq][l*32+col]
        float* qkA   = smem + 4416;   // 4 [hl*2+l]
        float* qkB   = qkA + 4;
        float* den   = qkB + 4;
        float* hs0   = den + 4;
        float* hs1   = hs0 + 4;
        if (tid < 64) {
            int l = tid >> 5, d = tid & 31;
            qs[l * 32 + d] = A.qd[(size_t)(bl0 + l) * 128 + hg * 32 + d];
        }
        {   // 2 contiguous cit rows per tensor: 256 float4 each
            ((float4*)ci0s)[tid] = ((const float4*)(A.cit + ((size_t)b * 512 + l0) * 512))[tid];
            ((float4*)ci1s)[tid] = ((const float4*)(A.cit + ((size_t)b * 512 + 256 + l0) * 512))[tid];
        }
        __syncthreads();
        if (tid < 4) {
            int hl = tid >> 1, l = tid & 1;
            float a = 0.f, c = 0.f;
#pragma unroll
            for (int d = 0; d < 16; ++d) {
                float qv = qs[l * 32 + hl * 16 + d];
                int wr = 128 + hg * 32 + hl * 16 + d;
                a += qv * A.uu_in_w[(size_t)wr * 128 + 126];
                c += qv * A.uu_in_w[(size_t)wr * 128 + 127];
            }
            qkA[tid] = a; qkB[tid] = c;
        }
        __syncthreads();
        {   // scores: lane <-> n (two chunks), coalesced kT reads
            const float* kp = A.kbaseT + ((size_t)b * 128 + hg * 32) * 512 + tid;
            float acc[2][2][2];    // [chunk][l][hl]
#pragma unroll
            for (int r = 0; r < 2; ++r)
#pragma unroll
                for (int l = 0; l < 2; ++l) { acc[r][l][0] = 0.f; acc[r][l][1] = 0.f; }
#pragma unroll 8
            for (int d = 0; d < 32; ++d) {
                float kv0 = kp[(size_t)d * 512];
                float kv1 = kp[(size_t)d * 512 + 256];
                int hl = d >> 4;
#pragma unroll
                for (int l = 0; l < 2; ++l) {
                    float qv = qs[l * 32 + d];
                    acc[0][l][hl] += qv * kv0;
                    acc[1][l][hl] += qv * kv1;
                }
            }
#pragma unroll
            for (int r = 0; r < 2; ++r) {
                int n = tid + r * 256;
#pragma unroll
                for (int l = 0; l < 2; ++l) {
                    float c0 = ci0s[l * 512 + n], c1 = ci1s[l * 512 + n];
#pragma unroll
                    for (int hl = 0; hl < 2; ++hl) {
                        int g = hl * 2 + l;
                        sc[g * 512 + n] = (acc[r][l][hl] + c0 * qkA[g] + c1 * qkB[g]) * 0.25f;
                    }
                }
            }
        }
        __syncthreads();
        {   // softmax + ci sums: 4 groups x 64 lanes
            int g = tid >> 6, j = tid & 63;
            int l = g & 1;
            float* row = sc + g * 512;
            const float* c0r = ci0s + l * 512;
            const float* c1r = ci1s + l * 512;
            float mx = -1e30f;
#pragma unroll
            for (int n = j; n < 512; n += 64) mx = fmaxf(mx, row[n]);
#pragma unroll
            for (int off = 32; off; off >>= 1) mx = fmaxf(mx, __shfl_down(mx, off, 64));
            mx = __shfl(mx, 0, 64);
            float s = 0.f, a0 = 0.f, a1 = 0.f;
#pragma unroll
            for (int n = j; n < 512; n += 64) {
                float ev = __expf(row[n] - mx);
                row[n] = ev;
                s += ev; a0 += ev * c0r[n]; a1 += ev * c1r[n];
            }
#pragma unroll
            for (int off = 32; off; off >>= 1) {
                s  += __shfl_down(s, off, 64);
                a0 += __shfl_down(a0, off, 64);
                a1 += __shfl_down(a1, off, 64);
            }
            if (j == 0) { den[g] = s; hs0[g] = a0; hs1[g] = a1; }
        }
        __syncthreads();
        {   // V pass partials: (col, l, n-quarter)
            int col = tid & 31, l = (tid >> 5) & 1, nq = tid >> 6;
            int colglob = hg * 32 + col;
            int g = (col >> 4) * 2 + l;
            const float* vcol = A.vbase + ((size_t)b * 512 + nq * 128) * 128 + colglob;
            const float* p = sc + g * 512 + nq * 128;
            float acc = 0.f;
#pragma unroll 8
            for (int n = 0; n < 128; ++n) acc += p[n] * vcol[(size_t)n * 128];
            vpart[nq * 64 + l * 32 + col] = acc;
        }
        __syncthreads();
        if (tid < 64) {
            int col = tid & 31, l = tid >> 5;
            int colglob = hg * 32 + col;
            int g = (col >> 4) * 2 + l;
            float sum = vpart[tid] + vpart[64 + tid] + vpart[128 + tid] + vpart[192 + tid];
            float wv126 = A.uu_in_w[(size_t)(256 + colglob) * 128 + 126];
            float wv127 = A.uu_in_w[(size_t)(256 + colglob) * 128 + 127];
            A.ouu[(size_t)(bl0 + l) * 128 + colglob] =
                (sum + hs0[g] * wv126 + hs1[g] * wv127) / den[g];
        }
    }
}

// epilogue: 256 blocks x 4 rows: y = Cuu@ouu + Cta@ota + Cdu@odu + bcomb; spread BN stats
__global__ __launch_bounds__(256) void epilogue_kernel(
    const float* __restrict__ ouu, const float* __restrict__ ota,
    const float* __restrict__ odu,
    const float* __restrict__ Cuu, const float* __restrict__ Cta,
    const float* __restrict__ Cdu, const float* __restrict__ bcomb,
    float* __restrict__ y, float* __restrict__ gstat)
{
    __shared__ __align__(16) float xs[4 * 384];
    __shared__ float vp[512];
    int m0 = blockIdx.x * 4;
    int tid = threadIdx.x;
    for (int i = tid; i < 1536; i += 256) {
        int r = i / 384, c = i - r * 384;
        float v;
        if (c < 128)      v = ouu[(size_t)(m0 + r) * 128 + c];
        else if (c < 256) v = ota[(size_t)(m0 + r) * 128 + c - 128];
        else              v = odu[(size_t)(m0 + r) * 128 + c - 256];
        xs[i] = v;
    }
    __syncthreads();
    int e = tid & 127, half = tid >> 7;
    const float4* cu4 = (const float4*)(Cuu + (size_t)e * 128);
    const float4* ct4 = (const float4*)(Cta + (size_t)e * 128);
    const float4* cd4 = (const float4*)(Cdu + (size_t)e * 128);
    const float4* xs4 = (const float4*)xs;   // row pitch 96 float4
    float bc = bcomb[e];
    float acc[2] = { bc, bc };
    int r0 = half * 2;
#pragma unroll 4
    for (int c = 0; c < 32; ++c) {
        float4 a = cu4[c], bb = ct4[c], d = cd4[c];
#pragma unroll
        for (int rr = 0; rr < 2; ++rr) {
            float4 xu = xs4[(r0 + rr) * 96 + c];
            float4 xt = xs4[(r0 + rr) * 96 + 32 + c];
            float4 xd = xs4[(r0 + rr) * 96 + 64 + c];
            acc[rr] += a.x * xu.x + a.y * xu.y + a.z * xu.z + a.w * xu.w
                     + bb.x * xt.x + bb.y * xt.y + bb.z * xt.z + bb.w * xt.w
                     + d.x * xd.x + d.y * xd.y + d.z * xd.z + d.w * xd.w;
        }
    }
#pragma unroll
    for (int rr = 0; rr < 2; ++rr)
        y[(size_t)(m0 + r0 + rr) * 128 + e] = acc[rr];
    vp[tid] = acc[0] + acc[1];
    vp[256 + tid] = acc[0] * acc[0] + acc[1] * acc[1];
    __syncthreads();
    if (tid < 128) {
        float* gs = gstat + (blockIdx.x & 15) * 256;
        atomicAdd(gs + tid, vp[tid] + vp[tid + 128]);
        atomicAdd(gs + 128 + tid, vp[256 + tid] + vp[256 + tid + 128]);
    }
}

__global__ __launch_bounds__(256) void bn_apply(
    const float* __restrict__ y, const float* __restrict__ gstat,
    const float* __restrict__ gamma, const float* __restrict__ beta,
    float* __restrict__ out)
{
    int gid = blockIdx.x * 256 + threadIdx.x;      // float4 index, 32768 total
    int c0 = (gid & 31) * 4;
    float4 v = ((const float4*)y)[gid];
    float r[4] = { v.x, v.y, v.z, v.w };
#pragma unroll
    for (int k = 0; k < 4; ++k) {
        int c = c0 + k;
        float s = 0.f, s2 = 0.f;
#pragma unroll
        for (int cp = 0; cp < 16; ++cp) {
            s  += gstat[cp * 256 + c];
            s2 += gstat[cp * 256 + 128 + c];
        }
        float mean = s * (1.f / 1024.f);
        float var = s2 * (1.f / 1024.f) - mean * mean;
        float inv = rsqrtf(var + 1e-5f);
        r[k] = fmaxf((r[k] - mean) * inv * gamma[c] + beta[c], 0.f);
    }
    float4 ov = { r[0], r[1], r[2], r[3] };
    ((float4*)out)[gid] = ov;
}

extern "C" void kernel_launch(void* const* d_in, const int* in_sizes, int n_in,
                              void* d_out, int out_size, void* d_ws, size_t ws_size,
                              hipStream_t stream)
{
    (void)in_sizes; (void)n_in; (void)out_size; (void)ws_size;
    const float* UUMat    = (const float*)d_in[0];
    const float* DUMat    = (const float*)d_in[1];
    const float* TAMat    = (const float*)d_in[2];
    const float* CIMat    = (const float*)d_in[3];
    const float* uu_in_w  = (const float*)d_in[4];
    const float* uu_in_b  = (const float*)d_in[5];
    const float* uu_out_w = (const float*)d_in[6];
    const float* uu_out_b = (const float*)d_in[7];
    const float* ta_in_w  = (const float*)d_in[8];
    const float* ta_in_b  = (const float*)d_in[9];
    const float* ta_out_w = (const float*)d_in[10];
    const float* ta_out_b = (const float*)d_in[11];
    const float* du_in_w  = (const float*)d_in[12];
    const float* du_in_b  = (const float*)d_in[13];
    const float* du_out_w = (const float*)d_in[14];
    const float* du_out_b = (const float*)d_in[15];
    const float* dim_w    = (const float*)d_in[16];
    const float* dim_b    = (const float*)d_in[17];
    const float* bn_g     = (const float*)d_in[18];
    const float* bn_b     = (const float*)d_in[19];

    const int BL = 1024, BN = 2048;
    float* ws = (float*)d_ws;
    float* gstat  = ws; ws += 16 * 256;
    float* cit    = ws; ws += (size_t)4 * 512 * 512;
    float* qd     = ws; ws += (size_t)BL * 128;
    float* kbaseT = ws; ws += (size_t)BN * 128;   // [b][128][512]
    float* vbase  = ws; ws += (size_t)BN * 128;
    float* qta    = ws; ws += (size_t)BL * 128;
    float* ktaT   = ws; ws += (size_t)BL * 128;   // [b][128][256]
    float* vta    = ws; ws += (size_t)BL * 128;
    float* qdu    = ws; ws += (size_t)BL * 128;
    float* kduT   = ws; ws += (size_t)BL * 128;   // [b][128][256]
    float* vdu    = ws; ws += (size_t)BL * 128;
    float* ouu    = ws; ws += (size_t)BL * 128;
    float* ota    = ws; ws += (size_t)BL * 128;
    float* odu    = ws; ws += (size_t)BL * 128;
    float* yy     = ws; ws += (size_t)BL * 128;
    float* Cuu    = ws; ws += 128 * 128;
    float* Cta    = ws; ws += 128 * 128;
    float* Cdu    = ws; ws += 128 * 128;
    float* bcomb  = ws; ws += 128;

    PreArgs P;
    P.x[0] = DUMat; P.W[0] = uu_in_w;             P.bia[0] = uu_in_b;       P.out[0] = qd;     P.Kdim[0] = 128; P.transNb[0] = 0;
    P.x[1] = DUMat; P.W[1] = ta_in_w;             P.bia[1] = ta_in_b;       P.out[1] = qta;    P.Kdim[1] = 128; P.transNb[1] = 0;
    P.x[2] = TAMat; P.W[2] = ta_in_w + 128 * 128; P.bia[2] = ta_in_b + 128; P.out[2] = ktaT;   P.Kdim[2] = 128; P.transNb[2] = 256;
    P.x[3] = TAMat; P.W[3] = ta_in_w + 256 * 128; P.bia[3] = ta_in_b + 256; P.out[3] = vta;    P.Kdim[3] = 128; P.transNb[3] = 0;
    P.x[4] = DUMat; P.W[4] = du_in_w;             P.bia[4] = du_in_b;       P.out[4] = qdu;    P.Kdim[4] = 128; P.transNb[4] = 0;
    P.x[5] = DUMat; P.W[5] = du_in_w + 128 * 128; P.bia[5] = du_in_b + 128; P.out[5] = kduT;   P.Kdim[5] = 128; P.transNb[5] = 256;
    P.x[6] = DUMat; P.W[6] = du_in_w + 256 * 128; P.bia[6] = du_in_b + 256; P.out[6] = vdu;    P.Kdim[6] = 128; P.transNb[6] = 0;
    P.x[7] = UUMat; P.W[7] = uu_in_w + 128 * 128; P.bia[7] = uu_in_b + 128; P.out[7] = kbaseT; P.Kdim[7] = 126; P.transNb[7] = 512;
    P.x[8] = UUMat; P.W[8] = uu_in_w + 256 * 128; P.bia[8] = uu_in_b + 256; P.out[8] = vbase;  P.Kdim[8] = 126; P.transNb[8] = 0;
    P.CIMat = CIMat; P.cit = cit;
    P.dim_w = dim_w; P.dim_b = dim_b;
    P.uu_ow = uu_out_w; P.uu_ob = uu_out_b;
    P.ta_ow = ta_out_w; P.ta_ob = ta_out_b;
    P.du_ow = du_out_w; P.du_ob = du_out_b;
    P.Cuu = Cuu; P.Cta = Cta; P.Cdu = Cdu; P.bcomb = bcomb;
    P.gstat = gstat;

    AttnArgs T;
    T.qd = qd; T.kbaseT = kbaseT; T.vbase = vbase; T.cit = cit;
    T.qta = qta; T.ktaT = ktaT; T.vta = vta;
    T.qdu = qdu; T.kduT = kduT; T.vdu = vdu;
    T.uu_in_w = uu_in_w;
    T.ouu = ouu; T.ota = ota; T.odu = odu;

    hipLaunchKernelGGL(pre_fused, dim3(1856), dim3(256), 0, stream, P);
    hipLaunchKernelGGL(attn_kernel, dim3(3072), dim3(256), 0, stream, T);
    hipLaunchKernelGGL(epilogue_kernel, dim3(256), dim3(256), 0, stream,
                       ouu, ota, odu, Cuu, Cta, Cdu, bcomb, yy, gstat);
    hipLaunchKernelGGL(bn_apply, dim3(128), dim3(256), 0, stream,
                       yy, gstat, bn_g, bn_b, (float*)d_out);
}